// Round 9
// baseline (176.835 us; speedup 1.0000x reference)
//
#include <hip/hip_runtime.h>
#include <hip/hip_bf16.h>
#include <math.h>

#define BB 8
#define NN 512
#define DD 256
#define BNT 4096   // B*N

typedef __attribute__((ext_vector_type(8))) short short8;
typedef __attribute__((ext_vector_type(4))) float f32x4;

// Workspace layout (float offsets). ~18.2 MB.
#define OFF_S0T   0u         // bf16 [8][256][512]   s0T[b][d][i]
#define OFF_GC    524288u    // bf16 [4096][1536]    Gcat[b*512+j][r*256+d]
#define OFF_WCT   3670016u   // bf16 [256][1536]     WcT[e][r*256+d] = relW[r][d][e]
#define OFF_WBT   3866624u   // bf16 [1024][256]     Wbig^T (c rows, k=d)
#define OFF_BB    3997696u   // fp32 [1024]          h1b|outb
#define OFF_CNT   3998720u   // u16  [4096][8]       per-(b,j) relation counts r=0..5
#define OFF_REL   4015104u   // u8   [8][512][512]   relation codes (self=6)

// d_out layout (floats)
#define OUT0_OFF   0u        // output  [8][512][256]
#define INTERP_OFF 1048576u  // interp  [3][4096]
#define SYM_OFF    1060864u  // symbols [8][512][256]

__device__ __forceinline__ float gelu_exact(float x) {
    return 0.5f * x * (1.0f + erff(x * 0.70710678118654752f));
}

__device__ __forceinline__ ushort f2bf(float x) {
    __hip_bfloat16 h = __float2bfloat16(x);
    union { __hip_bfloat16 b; ushort u; } cv;
    cv.b = h;
    return cv.u;
}

// Pack 8 fp32 -> bf16x8 fragment.
__device__ __forceinline__ short8 pack_bf8(float4 x, float4 y) {
    union { ushort u[8]; short8 v; } o;
    o.u[0] = f2bf(x.x); o.u[1] = f2bf(x.y); o.u[2] = f2bf(x.z); o.u[3] = f2bf(x.w);
    o.u[4] = f2bf(y.x); o.u[5] = f2bf(y.y); o.u[6] = f2bf(y.z); o.u[7] = f2bf(y.w);
    return o.v;
}

// Async global->LDS DMA, 16B per lane. LDS dest is wave-uniform base +
// lane*16; global src is per-lane.
typedef __attribute__((address_space(3))) unsigned int  lds_u32;
typedef __attribute__((address_space(1))) unsigned int  glb_u32;
__device__ __forceinline__ void gload16(const void* g, void* l) {
    __builtin_amdgcn_global_load_lds((const glb_u32*)g, (lds_u32*)l, 16, 0, 0);
}

// Branch-free classification (reference if/elif priority, applied in reverse).
__device__ __forceinline__ int rel_of(float dx, float dy) {
    int r = (fabsf(dx) < 0.3f && fabsf(dy) < 0.3f) ? 4 : 5;
    r = (dx >  0.5f) ? 3 : r;
    r = (dx < -0.5f) ? 2 : r;
    r = (dy < -0.5f) ? 1 : r;
    r = (dy >  0.5f) ? 0 : r;
    return r;
}

// One-hot bf16 fragment from 8 relation-code bytes: 1.0 where code==rr.
__device__ __forceinline__ short8 onehot8(uint2 cw, unsigned rr) {
    union { ushort u[8]; short8 v; } o;
    unsigned m = rr * 0x01010101u;
    unsigned x = cw.x ^ m, y = cw.y ^ m;
#pragma unroll
    for (int t = 0; t < 4; t++) {
        o.u[t]     = (((x >> (8 * t)) & 255u) == 0u) ? 0x3F80 : 0;
        o.u[t + 4] = (((y >> (8 * t)) & 255u) == 0u) ? 0x3F80 : 0;
    }
    return o.v;
}

// EXACT per-byte zero mask (no cross-byte borrow; bit7 set iff byte==0).
__device__ __forceinline__ unsigned zbyte_mask(unsigned t) {
    return ~(((t & 0x7F7F7F7Fu) + 0x7F7F7F7Fu) | t) & 0x80808080u;
}

// 64x64 tile, 4 waves (2x2). Fragment layout (m89/m91 verified):
// A: m=lane&15, k=quad*8+j; B: n=lane&15, k=quad*8+j;
// C/D: col=lane&15, row=quad*4+reg.
// LDS B-panel layout: 16B cell (k-octet m, col c) at ushort (m*64+c)*8 ->
// reads are lane-consecutive (conflict-free) and staging is lane-linear
// for global_load_lds (chunk m = one wave-gload of 1KB).
#define WAVE_IDS()                                             \
    const int lane = tid & 63, w = tid >> 6;                   \
    const int wm = w >> 1, wn = w & 1;                         \
    const int quad = lane >> 4, l15 = lane & 15;

#define ACC_INIT()                                             \
    f32x4 acc[2][2];                                           \
    _Pragma("unroll") for (int mt = 0; mt < 2; mt++)           \
    _Pragma("unroll") for (int nt = 0; nt < 2; nt++)           \
        acc[mt][nt] = (f32x4){0.f, 0.f, 0.f, 0.f};

#define MFMA4(a0, a1, b0, b1)                                                     \
    acc[0][0] = __builtin_amdgcn_mfma_f32_16x16x32_bf16(a0, b0, acc[0][0], 0, 0, 0); \
    acc[0][1] = __builtin_amdgcn_mfma_f32_16x16x32_bf16(a0, b1, acc[0][1], 0, 0, 0); \
    acc[1][0] = __builtin_amdgcn_mfma_f32_16x16x32_bf16(a1, b0, acc[1][0], 0, 0, 0); \
    acc[1][1] = __builtin_amdgcn_mfma_f32_16x16x32_bf16(a1, b1, acc[1][1], 0, 0, 0);

// front block ranges
#define FB_WCT   0     // 96 blocks: relW -> WcT transpose tiles
#define FB_H1    96    // 48 blocks: h1W -> WbT
#define FB_OUTW  144   // 16 blocks: outW -> WbT
#define FB_OUTI  160   // 12 blocks: outI init
#define FB_BB    172   // 1 block:   bbig init
#define FB_GATH  173   // 128 blocks: gather + s0T transpose
#define FB_CLS   301   // 512 blocks: classify + counts
#define FB_TOTAL 813

// ---------------------------------------------------------------- front ---
__global__ __launch_bounds__(256) void front_kernel(
    const int* __restrict__ ids, const float* __restrict__ positions,
    const float* __restrict__ symt, const float* __restrict__ layt,
    const float* __restrict__ relW, const float* __restrict__ h1W,
    const float* __restrict__ outW, const float* __restrict__ h1b,
    const float* __restrict__ outb, const float* __restrict__ h2b,
    ushort* __restrict__ WcT, ushort* __restrict__ WbT,
    float* __restrict__ bbig, float* __restrict__ outI,
    float* __restrict__ symOut, ushort* __restrict__ s0T,
    unsigned char* __restrict__ rel, ushort* __restrict__ cnts)
{
    __shared__ float shbuf[32 * 257];   // 32.9 KB: transpose tiles / gather / classify
    int blk = blockIdx.x, tid = threadIdx.x;
    if (blk < FB_OUTI) {
        // ---- coalesced 64x64 LDS-transpose tiles (sh stride 65) ----
        int kl = tid & 63, g4 = tid >> 6;       // lane-col, row-group
        const float* src; int srow, scol;       // src[(srow+rl)*256 + scol+el]
        ushort* dst; int drow, dstride;         // dst[(drow+el)*dstride + dcol+kl]
        int dcol;
        if (blk < FB_H1) {
            int t = blk, rdt = t >> 2, et = t & 3;
            src = relW; srow = rdt * 64; scol = et * 64;
            dst = WcT; drow = et * 64; dstride = 1536; dcol = rdt * 64;
        } else if (blk < FB_OUTW) {
            int t = blk - FB_H1, r = t >> 4, dt = (t >> 2) & 3, et = t & 3;
            src = h1W + (size_t)r * DD * DD; srow = dt * 64; scol = et * 64;
            dst = WbT; drow = r * 256 + et * 64; dstride = 256; dcol = dt * 64;
        } else {
            int t = blk - FB_OUTW, dt = t >> 2, et = t & 3;
            src = outW; srow = dt * 64; scol = et * 64;
            dst = WbT; drow = 768 + et * 64; dstride = 256; dcol = dt * 64;
        }
#pragma unroll
        for (int p = 0; p < 16; p++) {
            int rl = p * 4 + g4;
            shbuf[rl * 65 + kl] = src[(size_t)(srow + rl) * 256 + scol + kl];
        }
        __syncthreads();
#pragma unroll
        for (int q = 0; q < 16; q++) {
            int el = q * 4 + g4;
            dst[(size_t)(drow + el) * dstride + dcol + kl] = f2bf(shbuf[kl * 65 + el]);
        }
    } else if (blk < FB_BB) {
        int idx = (blk - FB_OUTI) * 256 + tid;   // [0, 3072)
        float v = h2b[idx >> 10];
        ((float4*)outI)[idx] = (float4){v, v, v, v};
    } else if (blk < FB_GATH) {
        ((float4*)bbig)[tid] = (tid < 192) ? ((const float4*)h1b)[tid]
                                           : ((const float4*)outb)[tid - 192];
    } else if (blk < FB_CLS) {
        // gather + LDS transpose -> symOut (fp32) and s0T (bf16 [b][d][i])
        int row0 = (blk - FB_GATH) * 32;         // global row
        int b = row0 >> 9, i0 = row0 & 511;
        int rl = tid >> 3, dq = (tid & 7) * 4;
        int row = row0 + rl;
        int id = ids[row];
#pragma unroll
        for (int u = 0; u < 8; u++) {
            int d = dq + u * 32;
            float4 a = *(const float4*)&symt[(size_t)id * DD + d];
            float4 c = *(const float4*)&layt[(size_t)id * DD + d];
            float4 v = {a.x + c.x, a.y + c.y, a.z + c.z, a.w + c.w};
            *(float4*)&symOut[(size_t)row * DD + d] = v;
            shbuf[rl * 257 + d + 0] = v.x;
            shbuf[rl * 257 + d + 1] = v.y;
            shbuf[rl * 257 + d + 2] = v.z;
            shbuf[rl * 257 + d + 3] = v.w;
        }
        __syncthreads();
        int dd = tid;                            // 0..255
        union { ushort u[32]; uint4 q[4]; } pk;
#pragma unroll
        for (int ii = 0; ii < 32; ii++) pk.u[ii] = f2bf(shbuf[ii * 257 + dd]);
        ushort* dst = s0T + ((size_t)(b * DD + dd)) * 512 + i0;
#pragma unroll
        for (int q = 0; q < 4; q++) ((uint4*)dst)[q] = pk.q[q];
    } else {
        float* px = shbuf;
        float* py = shbuf + NN;
        int blk2 = blk - FB_CLS;                 // [0,512)
        int b = blk2 >> 6;
        int j0 = (blk2 & 63) << 3;
        int jl = tid >> 5, sub = tid & 31;       // 8 j's x 32 workers x 16 i's
        for (int i = tid; i < NN; i += 256) {
            float2 p = ((const float2*)positions)[b * NN + i];
            px[i] = p.x; py[i] = p.y;
        }
        __syncthreads();
        int j = j0 + jl;
        float xj = px[j], yj = py[j];
        union { unsigned char u8[16]; unsigned wd[4]; uint4 v; } codes;
#pragma unroll
        for (int t = 0; t < 16; t++) {
            int i = sub * 16 + t;
            int r = rel_of(xj - px[i], yj - py[i]);
            r = (i == j) ? 6 : r;
            codes.u8[t] = (unsigned char)r;
        }
        *(uint4*)&rel[((size_t)(b * NN + j)) * NN + sub * 16] = codes.v;
        // per-(j,r) counts: EXACT zero-byte mask, then 32-lane reduce.
        int cnt[6];
#pragma unroll
        for (int r = 0; r < 6; r++) {
            unsigned m = (unsigned)r * 0x01010101u;
            int c = 0;
#pragma unroll
            for (int k = 0; k < 4; k++)
                c += __builtin_popcount(zbyte_mask(codes.wd[k] ^ m));
            cnt[r] = c;
        }
#pragma unroll
        for (int r = 0; r < 6; r++) {
            cnt[r] += __shfl_xor(cnt[r], 1);
            cnt[r] += __shfl_xor(cnt[r], 2);
            cnt[r] += __shfl_xor(cnt[r], 4);
            cnt[r] += __shfl_xor(cnt[r], 8);
            cnt[r] += __shfl_xor(cnt[r], 16);
        }
        if (sub == 0) {
            uint4 pq;
            pq.x = (unsigned)cnt[0] | ((unsigned)cnt[1] << 16);
            pq.y = (unsigned)cnt[2] | ((unsigned)cnt[3] << 16);
            pq.z = (unsigned)cnt[4] | ((unsigned)cnt[5] << 16);
            pq.w = 0u;
            *(uint4*)&cnts[((size_t)(b * NN + j)) * 8] = pq;
        }
    }
}

// ------------------------------------------------------------------ aggT --
// G[b][j][r*256+d] = sum_i 1[rel(j,i)=r] * s0[b][i][d]
// Whole B-panel (64 d x 512 i = 64 KB) staged ONCE into LDS; ONE barrier;
// then 16 straight-line K-steps (no inner barriers). One-hot A in-register
// from direct global code loads (compiler-pipelined). Plain bf16 stores.
// Grid (4 dt, 8 jt, 48 b*6+r) = 1536 blocks, 64 KB LDS -> 2 blocks/CU.
__global__ __launch_bounds__(256) void aggT_kernel(
    const unsigned char* __restrict__ rel, const ushort* __restrict__ s0T,
    ushort* __restrict__ Gc)
{
    __shared__ ushort Bls[64 * 512];   // [i-octet m][d-col] 16B cells = 64 KB
    int tid = threadIdx.x;
    int z = blockIdx.z;
    int b = z / 6;
    unsigned rr = (unsigned)(z - b * 6);
    int row0 = blockIdx.y * 64;   // j
    int col0 = blockIdx.x * 64;   // d
    WAVE_IDS();
    ACC_INIT();
    const ushort* gB = s0T + ((size_t)(b * DD) + col0 + lane) * 512;
#pragma unroll
    for (int t = 0; t < 16; t++) {
        int m = w * 16 + t;
        gload16(gB + m * 8, &Bls[m * 512]);
    }
    const unsigned char* gC0 = rel + ((size_t)(b * NN) + row0 + wm * 32 + l15) * NN + quad * 8;
    const unsigned char* gC1 = gC0 + 16 * NN;
    __syncthreads();
#pragma unroll
    for (int s = 0; s < 16; s++) {
        uint2 c0 = *(const uint2*)(gC0 + s * 32);
        uint2 c1 = *(const uint2*)(gC1 + s * 32);
        short8 a0 = onehot8(c0, rr);
        short8 a1 = onehot8(c1, rr);
        short8 b0 = *(const short8*)&Bls[((s * 4 + quad) * 64 + wn * 32 + l15) * 8];
        short8 b1 = *(const short8*)&Bls[((s * 4 + quad) * 64 + wn * 32 + 16 + l15) * 8];
        MFMA4(a0, a1, b0, b1);
    }
#pragma unroll
    for (int mt = 0; mt < 2; mt++)
#pragma unroll
        for (int nt = 0; nt < 2; nt++)
#pragma unroll
            for (int v = 0; v < 4; v++) {
                int j = row0 + wm * 32 + mt * 16 + quad * 4 + v;
                int d = col0 + wn * 32 + nt * 16 + l15;
                Gc[((size_t)(b * NN) + j) * 1536 + rr * 256 + d] =
                    f2bf(acc[mt][nt][v]);
            }
}

// ----------------------------------------------------------------- projC --
// symOut[b*512+j][e] += sum_{r,d} Gc[j][r*256+d] * relW[r][d][e]
//                     + sum_r counts[j][r] * relb[r][e]
// K=1536 as 3 chunks of 512; B-chunk (64 KB) staged whole, pipelined
// (issue chunk c+1 before computing chunk c) -> 3 barriers total.
// A direct-to-reg 16B bf16 loads from Gc (L2-hot, shared by 4 col-blocks).
// Single writer per output (no atomics). Grid (4 et, 64 jt), 128 KB LDS.
__global__ __launch_bounds__(256) void projC_kernel(
    const ushort* __restrict__ Gc, const ushort* __restrict__ WcT,
    const ushort* __restrict__ cnts, const float* __restrict__ relb,
    float* __restrict__ symOut)
{
    __shared__ ushort Bls[2][64 * 512];   // 2 x 64 KB
    int tid = threadIdx.x;
    int row0 = blockIdx.y * 64;   // global row (b*512+j)
    int col0 = blockIdx.x * 64;   // e
    WAVE_IDS();
    ACC_INIT();
    const ushort* gB  = WcT + (size_t)(col0 + lane) * 1536;
    const ushort* gA0 = Gc + (size_t)(row0 + wm * 32 + l15) * 1536 + quad * 8;
    const ushort* gA1 = gA0 + (size_t)16 * 1536;

#define PJ_STAGE(zc, buf)                                         \
    _Pragma("unroll")                                             \
    for (int t = 0; t < 16; t++) {                                \
        int m = w * 16 + t;                                       \
        gload16(gB + (zc) * 512 + m * 8, &Bls[buf][m * 512]);     \
    }
#define PJ_COMPUTE(zc, buf)                                                       \
    _Pragma("unroll")                                                             \
    for (int s = 0; s < 16; s++) {                                                \
        short8 a0 = *(const short8*)(gA0 + (zc) * 512 + s * 32);                  \
        short8 a1 = *(const short8*)(gA1 + (zc) * 512 + s * 32);                  \
        short8 b0 = *(const short8*)&Bls[buf][((s * 4 + quad) * 64 + wn * 32 + l15) * 8]; \
        short8 b1 = *(const short8*)&Bls[buf][((s * 4 + quad) * 64 + wn * 32 + 16 + l15) * 8]; \
        MFMA4(a0, a1, b0, b1);                                                    \
    }

    PJ_STAGE(0, 0);
    __syncthreads();           // chunk0 ready
    PJ_STAGE(1, 1);            // issue chunk1 (lands under compute0)
    PJ_COMPUTE(0, 0);
    __syncthreads();           // chunk1 ready; buf0 free
    PJ_STAGE(2, 0);            // issue chunk2
    PJ_COMPUTE(1, 1);
    __syncthreads();           // chunk2 ready
    PJ_COMPUTE(2, 0);
#undef PJ_STAGE
#undef PJ_COMPUTE
    // epilogue: symOut = s0 + contrib + counts·relb (single writer)
#pragma unroll
    for (int mt = 0; mt < 2; mt++)
#pragma unroll
        for (int v = 0; v < 4; v++) {
            int row = row0 + wm * 32 + mt * 16 + quad * 4 + v;
            const ushort* cp = &cnts[(size_t)row * 8];
            float c0 = cp[0], c1 = cp[1], c2 = cp[2];
            float c3 = cp[3], c4 = cp[4], c5 = cp[5];
#pragma unroll
            for (int nt = 0; nt < 2; nt++) {
                int e = col0 + wn * 32 + nt * 16 + l15;
                float bias = c0 * relb[e]            + c1 * relb[DD + e]
                           + c2 * relb[2 * DD + e]   + c3 * relb[3 * DD + e]
                           + c4 * relb[4 * DD + e]   + c5 * relb[5 * DD + e];
                float* po = &symOut[(size_t)row * DD + e];
                *po = *po + acc[mt][nt][v] + bias;
            }
        }
}

// ----------------------------------------------------------------- gemm2 --
// symOut @ Wbig^T. Whole B-panel (64 c x 256 d = 32 KB) staged once; ONE
// barrier; 8 straight-line K-steps, A direct-to-reg fp32->bf16 (L2-hot).
// Col tiles <768: gelu + fused interp reduce (atomicAdd into outI pre-loaded
// with h2b). Else: out0. Grid (16,64) = 1024 blocks.
__global__ __launch_bounds__(256) void gemm2_kernel(
    const float* __restrict__ symOut, const ushort* __restrict__ WbT,
    const float* __restrict__ bbig, const float* __restrict__ h2W,
    float* __restrict__ out0, float* __restrict__ outI)
{
    __shared__ ushort Bls[32 * 512];   // [d-octet m][c] cells = 32 KB
    int tid = threadIdx.x;
    int row0 = blockIdx.y * 64, col0 = blockIdx.x * 64;
    WAVE_IDS();
    ACC_INIT();
    const ushort* gB = WbT + (size_t)(col0 + lane) * 256;
#pragma unroll
    for (int t = 0; t < 8; t++) {
        int m = w * 8 + t;
        gload16(gB + m * 8, &Bls[m * 512]);
    }
    const float* gA0 = symOut + (size_t)(row0 + wm * 32 + l15) * 256 + quad * 8;
    const float* gA1 = gA0 + 16 * 256;
    __syncthreads();
#pragma unroll
    for (int s = 0; s < 8; s++) {
        float4 x0 = *(const float4*)(gA0 + s * 32);
        float4 y0 = *(const float4*)(gA0 + s * 32 + 4);
        float4 x1 = *(const float4*)(gA1 + s * 32);
        float4 y1 = *(const float4*)(gA1 + s * 32 + 4);
        short8 a0 = pack_bf8(x0, y0);
        short8 a1 = pack_bf8(x1, y1);
        short8 b0 = *(const short8*)&Bls[((s * 4 + quad) * 64 + wn * 32 + l15) * 8];
        short8 b1 = *(const short8*)&Bls[((s * 4 + quad) * 64 + wn * 32 + 16 + l15) * 8];
        MFMA4(a0, a1, b0, b1);
    }
    if (col0 >= 768) {
#pragma unroll
        for (int nt = 0; nt < 2; nt++) {
            int c = col0 + wn * 32 + nt * 16 + l15;
            float bb = bbig[c];
#pragma unroll
            for (int mt = 0; mt < 2; mt++)
#pragma unroll
                for (int v = 0; v < 4; v++) {
                    int row = row0 + wm * 32 + mt * 16 + quad * 4 + v;
                    out0[(size_t)row * DD + (c - 768)] = acc[mt][nt][v] + bb;
                }
        }
    } else {
        int head = col0 >> 8;
        float part[2][4];
#pragma unroll
        for (int mt = 0; mt < 2; mt++)
#pragma unroll
            for (int v = 0; v < 4; v++) part[mt][v] = 0.f;
#pragma unroll
        for (int nt = 0; nt < 2; nt++) {
            int c = col0 + wn * 32 + nt * 16 + l15;
            float bb = bbig[c];
            float w2 = h2W[c];
#pragma unroll
            for (int mt = 0; mt < 2; mt++)
#pragma unroll
                for (int v = 0; v < 4; v++)
                    part[mt][v] += gelu_exact(acc[mt][nt][v] + bb) * w2;
        }
#pragma unroll
        for (int mt = 0; mt < 2; mt++)
#pragma unroll
            for (int v = 0; v < 4; v++) {
                float p = part[mt][v];
                p += __shfl_xor(p, 1); p += __shfl_xor(p, 2);
                p += __shfl_xor(p, 4); p += __shfl_xor(p, 8);
                if (l15 == 0) {
                    int row = row0 + wm * 32 + mt * 16 + quad * 4 + v;
                    atomicAdd(&outI[head * BNT + row], p);
                }
            }
    }
}

// ---------------------------------------------------------------- launch --
extern "C" void kernel_launch(void* const* d_in, const int* in_sizes, int n_in,
                              void* d_out, int out_size, void* d_ws, size_t ws_size,
                              hipStream_t stream)
{
    const int*   ids  = (const int*)d_in[0];
    const float* pos  = (const float*)d_in[1];
    const float* symt = (const float*)d_in[2];
    const float* layt = (const float*)d_in[3];
    const float* relW = (const float*)d_in[4];
    const float* relb = (const float*)d_in[5];
    const float* h1W  = (const float*)d_in[6];
    const float* h1b  = (const float*)d_in[7];
    const float* h2W  = (const float*)d_in[8];
    const float* h2b  = (const float*)d_in[9];
    const float* outW = (const float*)d_in[10];
    const float* outb = (const float*)d_in[11];
    float* out = (float*)d_out;
    float* ws  = (float*)d_ws;

    ushort* s0T  = (ushort*)(ws + OFF_S0T);
    ushort* Gc   = (ushort*)(ws + OFF_GC);
    ushort* WcT  = (ushort*)(ws + OFF_WCT);
    ushort* WbT  = (ushort*)(ws + OFF_WBT);
    float*  bbig = ws + OFF_BB;
    ushort* cnts = (ushort*)(ws + OFF_CNT);
    unsigned char* rel = (unsigned char*)(ws + OFF_REL);

    front_kernel<<<FB_TOTAL, 256, 0, stream>>>(ids, pos, symt, layt, relW, h1W, outW,
                                               h1b, outb, h2b, WcT, WbT, bbig,
                                               out + INTERP_OFF, out + SYM_OFF, s0T,
                                               rel, cnts);
    aggT_kernel<<<dim3(4, 8, 48), 256, 0, stream>>>(rel, s0T, Gc);
    projC_kernel<<<dim3(4, 64), 256, 0, stream>>>(Gc, WcT, cnts, relb,
                                                  out + SYM_OFF);
    gemm2_kernel<<<dim3(16, 64), 256, 0, stream>>>(out + SYM_OFF, WbT,
                                                   bbig, h2W,
                                                   out + OUT0_OFF, out + INTERP_OFF);
}

// Round 10
// 161.674 us; speedup vs baseline: 1.0938x; 1.0938x over previous
//
#include <hip/hip_runtime.h>
#include <hip/hip_bf16.h>
#include <math.h>

#define BB 8
#define NN 512
#define DD 256
#define BNT 4096   // B*N

typedef __attribute__((ext_vector_type(8))) short short8;
typedef __attribute__((ext_vector_type(4))) float f32x4;

// Workspace layout (float offsets). ~18.2 MB.
#define OFF_S0T   0u         // bf16 [8][256][512]   s0T[b][d][i]
#define OFF_GC    524288u    // bf16 [4096][1536]    Gcat[b*512+j][r*256+d]
#define OFF_WCT   3670016u   // bf16 [256][1536]     WcT[e][r*256+d] = relW[r][d][e]
#define OFF_WBT   3866624u   // bf16 [1024][256]     Wbig^T (c rows, k=d)
#define OFF_BB    3997696u   // fp32 [1024]          h1b|outb
#define OFF_CNT   3998720u   // u16  [4096][8]       per-(b,j) relation counts r=0..5
#define OFF_REL   4015104u   // u8   [8][512][512]   relation codes (self=6)

// d_out layout (floats)
#define OUT0_OFF   0u        // output  [8][512][256]
#define INTERP_OFF 1048576u  // interp  [3][4096]
#define SYM_OFF    1060864u  // symbols [8][512][256]

__device__ __forceinline__ float gelu_exact(float x) {
    return 0.5f * x * (1.0f + erff(x * 0.70710678118654752f));
}

__device__ __forceinline__ ushort f2bf(float x) {
    __hip_bfloat16 h = __float2bfloat16(x);
    union { __hip_bfloat16 b; ushort u; } cv;
    cv.b = h;
    return cv.u;
}

// Pack 8 fp32 -> bf16x8 fragment.
__device__ __forceinline__ short8 pack_bf8(float4 x, float4 y) {
    union { ushort u[8]; short8 v; } o;
    o.u[0] = f2bf(x.x); o.u[1] = f2bf(x.y); o.u[2] = f2bf(x.z); o.u[3] = f2bf(x.w);
    o.u[4] = f2bf(y.x); o.u[5] = f2bf(y.y); o.u[6] = f2bf(y.z); o.u[7] = f2bf(y.w);
    return o.v;
}

// Async global->LDS DMA, 16B per lane. LDS dest is wave-uniform base +
// lane*16; global src is per-lane (pre-swizzled source = HK pattern).
typedef __attribute__((address_space(3))) unsigned int  lds_u32;
typedef __attribute__((address_space(1))) unsigned int  glb_u32;
__device__ __forceinline__ void gload16(const void* g, void* l) {
    __builtin_amdgcn_global_load_lds((const glb_u32*)g, (lds_u32*)l, 16, 0, 0);
}

// Branch-free classification (reference if/elif priority, applied in reverse).
__device__ __forceinline__ int rel_of(float dx, float dy) {
    int r = (fabsf(dx) < 0.3f && fabsf(dy) < 0.3f) ? 4 : 5;
    r = (dx >  0.5f) ? 3 : r;
    r = (dx < -0.5f) ? 2 : r;
    r = (dy < -0.5f) ? 1 : r;
    r = (dy >  0.5f) ? 0 : r;
    return r;
}

// One-hot bf16 fragment from 8 relation-code bytes: 1.0 where code==rr.
__device__ __forceinline__ short8 onehot8(uint2 cw, unsigned rr) {
    union { ushort u[8]; short8 v; } o;
    unsigned m = rr * 0x01010101u;
    unsigned x = cw.x ^ m, y = cw.y ^ m;
#pragma unroll
    for (int t = 0; t < 4; t++) {
        o.u[t]     = (((x >> (8 * t)) & 255u) == 0u) ? 0x3F80 : 0;
        o.u[t + 4] = (((y >> (8 * t)) & 255u) == 0u) ? 0x3F80 : 0;
    }
    return o.v;
}

// EXACT per-byte zero mask (no cross-byte borrow; bit7 set iff byte==0).
__device__ __forceinline__ unsigned zbyte_mask(unsigned t) {
    return ~(((t & 0x7F7F7F7Fu) + 0x7F7F7F7Fu) | t) & 0x80808080u;
}

// 64x64 tile, 4 waves (2x2). Fragment layout (m89/m91 verified):
// A: m=lane&15, k=quad*8+j; B: n=lane&15, k=quad*8+j;
// C/D: col=lane&15, row=quad*4+reg.
//
// LDS B-panel: row-major [row][K] with XOR-swizzled 16B cells.
// Stage (coalesced): one wave-load = one contiguous 1KB row span; lane l's
// cell l is fetched from source chunk (l ^ (row&7)).
// Read: chunk io of row d lives at cell (io ^ (d&7)) -> banks spread 8-way,
// residual 2-way (free, m136).
#define WAVE_IDS()                                             \
    const int lane = tid & 63, w = tid >> 6;                   \
    const int wm = w >> 1, wn = w & 1;                         \
    const int quad = lane >> 4, l15 = lane & 15;

#define ACC_INIT()                                             \
    f32x4 acc[2][2];                                           \
    _Pragma("unroll") for (int mt = 0; mt < 2; mt++)           \
    _Pragma("unroll") for (int nt = 0; nt < 2; nt++)           \
        acc[mt][nt] = (f32x4){0.f, 0.f, 0.f, 0.f};

#define MFMA4(a0, a1, b0, b1)                                                     \
    acc[0][0] = __builtin_amdgcn_mfma_f32_16x16x32_bf16(a0, b0, acc[0][0], 0, 0, 0); \
    acc[0][1] = __builtin_amdgcn_mfma_f32_16x16x32_bf16(a0, b1, acc[0][1], 0, 0, 0); \
    acc[1][0] = __builtin_amdgcn_mfma_f32_16x16x32_bf16(a1, b0, acc[1][0], 0, 0, 0); \
    acc[1][1] = __builtin_amdgcn_mfma_f32_16x16x32_bf16(a1, b1, acc[1][1], 0, 0, 0);

// front block ranges
#define FB_WCT   0     // 96 blocks: relW -> WcT transpose tiles
#define FB_H1    96    // 48 blocks: h1W -> WbT
#define FB_OUTW  144   // 16 blocks: outW -> WbT
#define FB_OUTI  160   // 12 blocks: outI init
#define FB_BB    172   // 1 block:   bbig init
#define FB_GATH  173   // 128 blocks: gather + s0T transpose
#define FB_CLS   301   // 512 blocks: classify + counts
#define FB_TOTAL 813

// ---------------------------------------------------------------- front ---
__global__ __launch_bounds__(256) void front_kernel(
    const int* __restrict__ ids, const float* __restrict__ positions,
    const float* __restrict__ symt, const float* __restrict__ layt,
    const float* __restrict__ relW, const float* __restrict__ h1W,
    const float* __restrict__ outW, const float* __restrict__ h1b,
    const float* __restrict__ outb, const float* __restrict__ h2b,
    ushort* __restrict__ WcT, ushort* __restrict__ WbT,
    float* __restrict__ bbig, float* __restrict__ outI,
    float* __restrict__ symOut, ushort* __restrict__ s0T,
    unsigned char* __restrict__ rel, ushort* __restrict__ cnts)
{
    __shared__ float shbuf[32 * 257];   // 32.9 KB: transpose tiles / gather / classify
    int blk = blockIdx.x, tid = threadIdx.x;
    if (blk < FB_OUTI) {
        // ---- coalesced 64x64 LDS-transpose tiles (sh stride 65) ----
        int kl = tid & 63, g4 = tid >> 6;       // lane-col, row-group
        const float* src; int srow, scol;       // src[(srow+rl)*256 + scol+el]
        ushort* dst; int drow, dstride;         // dst[(drow+el)*dstride + dcol+kl]
        int dcol;
        if (blk < FB_H1) {
            int t = blk, rdt = t >> 2, et = t & 3;
            src = relW; srow = rdt * 64; scol = et * 64;
            dst = WcT; drow = et * 64; dstride = 1536; dcol = rdt * 64;
        } else if (blk < FB_OUTW) {
            int t = blk - FB_H1, r = t >> 4, dt = (t >> 2) & 3, et = t & 3;
            src = h1W + (size_t)r * DD * DD; srow = dt * 64; scol = et * 64;
            dst = WbT; drow = r * 256 + et * 64; dstride = 256; dcol = dt * 64;
        } else {
            int t = blk - FB_OUTW, dt = t >> 2, et = t & 3;
            src = outW; srow = dt * 64; scol = et * 64;
            dst = WbT; drow = 768 + et * 64; dstride = 256; dcol = dt * 64;
        }
#pragma unroll
        for (int p = 0; p < 16; p++) {
            int rl = p * 4 + g4;
            shbuf[rl * 65 + kl] = src[(size_t)(srow + rl) * 256 + scol + kl];
        }
        __syncthreads();
#pragma unroll
        for (int q = 0; q < 16; q++) {
            int el = q * 4 + g4;
            dst[(size_t)(drow + el) * dstride + dcol + kl] = f2bf(shbuf[kl * 65 + el]);
        }
    } else if (blk < FB_BB) {
        int idx = (blk - FB_OUTI) * 256 + tid;   // [0, 3072)
        float v = h2b[idx >> 10];
        ((float4*)outI)[idx] = (float4){v, v, v, v};
    } else if (blk < FB_GATH) {
        ((float4*)bbig)[tid] = (tid < 192) ? ((const float4*)h1b)[tid]
                                           : ((const float4*)outb)[tid - 192];
    } else if (blk < FB_CLS) {
        // gather + LDS transpose -> symOut (fp32) and s0T (bf16 [b][d][i])
        int row0 = (blk - FB_GATH) * 32;         // global row
        int b = row0 >> 9, i0 = row0 & 511;
        int rl = tid >> 3, dq = (tid & 7) * 4;
        int row = row0 + rl;
        int id = ids[row];
#pragma unroll
        for (int u = 0; u < 8; u++) {
            int d = dq + u * 32;
            float4 a = *(const float4*)&symt[(size_t)id * DD + d];
            float4 c = *(const float4*)&layt[(size_t)id * DD + d];
            float4 v = {a.x + c.x, a.y + c.y, a.z + c.z, a.w + c.w};
            *(float4*)&symOut[(size_t)row * DD + d] = v;
            shbuf[rl * 257 + d + 0] = v.x;
            shbuf[rl * 257 + d + 1] = v.y;
            shbuf[rl * 257 + d + 2] = v.z;
            shbuf[rl * 257 + d + 3] = v.w;
        }
        __syncthreads();
        int dd = tid;                            // 0..255
        union { ushort u[32]; uint4 q[4]; } pk;
#pragma unroll
        for (int ii = 0; ii < 32; ii++) pk.u[ii] = f2bf(shbuf[ii * 257 + dd]);
        ushort* dst = s0T + ((size_t)(b * DD + dd)) * 512 + i0;
#pragma unroll
        for (int q = 0; q < 4; q++) ((uint4*)dst)[q] = pk.q[q];
    } else {
        float* px = shbuf;
        float* py = shbuf + NN;
        int blk2 = blk - FB_CLS;                 // [0,512)
        int b = blk2 >> 6;
        int j0 = (blk2 & 63) << 3;
        int jl = tid >> 5, sub = tid & 31;       // 8 j's x 32 workers x 16 i's
        for (int i = tid; i < NN; i += 256) {
            float2 p = ((const float2*)positions)[b * NN + i];
            px[i] = p.x; py[i] = p.y;
        }
        __syncthreads();
        int j = j0 + jl;
        float xj = px[j], yj = py[j];
        union { unsigned char u8[16]; unsigned wd[4]; uint4 v; } codes;
#pragma unroll
        for (int t = 0; t < 16; t++) {
            int i = sub * 16 + t;
            int r = rel_of(xj - px[i], yj - py[i]);
            r = (i == j) ? 6 : r;
            codes.u8[t] = (unsigned char)r;
        }
        *(uint4*)&rel[((size_t)(b * NN + j)) * NN + sub * 16] = codes.v;
        // per-(j,r) counts: EXACT zero-byte mask, then 32-lane reduce.
        int cnt[6];
#pragma unroll
        for (int r = 0; r < 6; r++) {
            unsigned m = (unsigned)r * 0x01010101u;
            int c = 0;
#pragma unroll
            for (int k = 0; k < 4; k++)
                c += __builtin_popcount(zbyte_mask(codes.wd[k] ^ m));
            cnt[r] = c;
        }
#pragma unroll
        for (int r = 0; r < 6; r++) {
            cnt[r] += __shfl_xor(cnt[r], 1);
            cnt[r] += __shfl_xor(cnt[r], 2);
            cnt[r] += __shfl_xor(cnt[r], 4);
            cnt[r] += __shfl_xor(cnt[r], 8);
            cnt[r] += __shfl_xor(cnt[r], 16);
        }
        if (sub == 0) {
            uint4 pq;
            pq.x = (unsigned)cnt[0] | ((unsigned)cnt[1] << 16);
            pq.y = (unsigned)cnt[2] | ((unsigned)cnt[3] << 16);
            pq.z = (unsigned)cnt[4] | ((unsigned)cnt[5] << 16);
            pq.w = 0u;
            *(uint4*)&cnts[((size_t)(b * NN + j)) * 8] = pq;
        }
    }
}

// ------------------------------------------------------------------ aggT --
// G[b][j][r*256+d] = sum_i 1[rel(j,i)=r] * s0[b][i][d]
// B panel (64 d-rows x 512 i) staged COALESCED: one wave-load = one 1KB row,
// source chunk pre-swizzled (c ^ (d&7)); read swizzled -> ~2-way banks.
// One barrier; 16 straight-line K-steps; codes direct (L1 line reuse).
// Grid (4 dt, 8 jt, 48 b*6+r) = 1536 blocks, 64 KB LDS -> 2 blocks/CU.
__global__ __launch_bounds__(256) void aggT_kernel(
    const unsigned char* __restrict__ rel, const ushort* __restrict__ s0T,
    ushort* __restrict__ Gc)
{
    __shared__ ushort Bls[64 * 512];   // [d-row][i], swizzled 16B cells = 64 KB
    int tid = threadIdx.x;
    int z = blockIdx.z;
    int b = z / 6;
    unsigned rr = (unsigned)(z - b * 6);
    int row0 = blockIdx.y * 64;   // j
    int col0 = blockIdx.x * 64;   // d
    WAVE_IDS();
    ACC_INIT();
#pragma unroll
    for (int t = 0; t < 16; t++) {
        int dl = w * 16 + t;
        const ushort* src = s0T + ((size_t)(b * DD) + col0 + dl) * 512
                            + (lane ^ (dl & 7)) * 8;
        gload16(src, &Bls[dl * 512]);
    }
    const unsigned char* gC0 = rel + ((size_t)(b * NN) + row0 + wm * 32 + l15) * NN + quad * 8;
    const unsigned char* gC1 = gC0 + 16 * NN;
    __syncthreads();
    const int d0 = wn * 32 + l15, d1 = d0 + 16;
    const int k0 = d0 & 7, k1 = d1 & 7;
#pragma unroll
    for (int s = 0; s < 16; s++) {
        uint2 c0 = *(const uint2*)(gC0 + s * 32);
        uint2 c1 = *(const uint2*)(gC1 + s * 32);
        short8 a0 = onehot8(c0, rr);
        short8 a1 = onehot8(c1, rr);
        int io = s * 4 + quad;
        short8 b0 = *(const short8*)&Bls[d0 * 512 + ((io ^ k0) * 8)];
        short8 b1 = *(const short8*)&Bls[d1 * 512 + ((io ^ k1) * 8)];
        MFMA4(a0, a1, b0, b1);
    }
#pragma unroll
    for (int mt = 0; mt < 2; mt++)
#pragma unroll
        for (int nt = 0; nt < 2; nt++)
#pragma unroll
            for (int v = 0; v < 4; v++) {
                int j = row0 + wm * 32 + mt * 16 + quad * 4 + v;
                int d = col0 + wn * 32 + nt * 16 + l15;
                Gc[((size_t)(b * NN) + j) * 1536 + rr * 256 + d] =
                    f2bf(acc[mt][nt][v]);
            }
}

// ----------------------------------------------------------------- projC --
// symOut[b*512+j][e] += sum_{r,d} Gc[j][r*256+d] * relW[r][d][e]
//                     + sum_r counts[j][r] * relb[r][e]
// K=1536 split over z (3 chunks of 512) -> 768 blocks, atomicAdd epilogue
// (bias folded in zc==0 only). B chunk (64 KB) staged coalesced+swizzled;
// A direct 16B reads from Gc (consecutive s -> L1 line reuse).
// Grid (4 et, 64 jt, 3 zc), 64 KB LDS -> 2 blocks/CU.
__global__ __launch_bounds__(256) void projC_kernel(
    const ushort* __restrict__ Gc, const ushort* __restrict__ WcT,
    const ushort* __restrict__ cnts, const float* __restrict__ relb,
    float* __restrict__ symOut)
{
    __shared__ ushort Bls[64 * 512];   // 64 KB
    int tid = threadIdx.x;
    int zc = blockIdx.z;
    int row0 = blockIdx.y * 64;   // global row (b*512+j)
    int col0 = blockIdx.x * 64;   // e
    WAVE_IDS();
    ACC_INIT();
#pragma unroll
    for (int t = 0; t < 16; t++) {
        int el = w * 16 + t;
        const ushort* src = WcT + (size_t)(col0 + el) * 1536 + zc * 512
                            + (lane ^ (el & 7)) * 8;
        gload16(src, &Bls[el * 512]);
    }
    const ushort* gA0 = Gc + (size_t)(row0 + wm * 32 + l15) * 1536 + zc * 512 + quad * 8;
    const ushort* gA1 = gA0 + (size_t)16 * 1536;
    __syncthreads();
    const int e0 = wn * 32 + l15, e1 = e0 + 16;
    const int k0 = e0 & 7, k1 = e1 & 7;
#pragma unroll
    for (int s = 0; s < 16; s++) {
        short8 a0 = *(const short8*)(gA0 + s * 32);
        short8 a1 = *(const short8*)(gA1 + s * 32);
        int io = s * 4 + quad;
        short8 b0 = *(const short8*)&Bls[e0 * 512 + ((io ^ k0) * 8)];
        short8 b1 = *(const short8*)&Bls[e1 * 512 + ((io ^ k1) * 8)];
        MFMA4(a0, a1, b0, b1);
    }
    // epilogue: atomic contrib add; bias (counts·relb) only from zc==0.
#pragma unroll
    for (int mt = 0; mt < 2; mt++)
#pragma unroll
        for (int v = 0; v < 4; v++) {
            int row = row0 + wm * 32 + mt * 16 + quad * 4 + v;
            float c0 = 0, c1 = 0, c2 = 0, c3 = 0, c4 = 0, c5 = 0;
            if (zc == 0) {
                const ushort* cp = &cnts[(size_t)row * 8];
                c0 = cp[0]; c1 = cp[1]; c2 = cp[2];
                c3 = cp[3]; c4 = cp[4]; c5 = cp[5];
            }
#pragma unroll
            for (int nt = 0; nt < 2; nt++) {
                int e = col0 + wn * 32 + nt * 16 + l15;
                float add = acc[mt][nt][v];
                if (zc == 0)
                    add += c0 * relb[e]          + c1 * relb[DD + e]
                         + c2 * relb[2 * DD + e] + c3 * relb[3 * DD + e]
                         + c4 * relb[4 * DD + e] + c5 * relb[5 * DD + e];
                atomicAdd(&symOut[(size_t)row * DD + e], add);
            }
        }
}

// ----------------------------------------------------------------- gemm2 --
// symOut @ Wbig^T. B panel (64 c x 256 d = 32 KB) staged coalesced
// (one wave-load = two 512B rows) + swizzled; ONE barrier; 8 straight-line
// K-steps, A direct fp32->bf16. Col tiles <768: gelu + fused interp reduce.
// Grid (16,64) = 1024 blocks, 32 KB LDS -> 4 blocks/CU.
__global__ __launch_bounds__(256) void gemm2_kernel(
    const float* __restrict__ symOut, const ushort* __restrict__ WbT,
    const float* __restrict__ bbig, const float* __restrict__ h2W,
    float* __restrict__ out0, float* __restrict__ outI)
{
    __shared__ ushort Bls[64 * 256];   // [c-row][d], swizzled 16B cells = 32 KB
    int tid = threadIdx.x;
    int row0 = blockIdx.y * 64, col0 = blockIdx.x * 64;
    WAVE_IDS();
    ACC_INIT();
#pragma unroll
    for (int t = 0; t < 8; t++) {
        int m = w * 8 + t;                       // row pair index
        int rl = m * 2 + (lane >> 5);            // row_local in [0,64)
        const ushort* src = WbT + (size_t)(col0 + rl) * 256
                            + (((lane & 31) ^ (rl & 7)) * 8);
        gload16(src, &Bls[m * 512]);
    }
    const float* gA0 = symOut + (size_t)(row0 + wm * 32 + l15) * 256 + quad * 8;
    const float* gA1 = gA0 + 16 * 256;
    __syncthreads();
    const int c0i = wn * 32 + l15, c1i = c0i + 16;
    const int k0 = c0i & 7, k1 = c1i & 7;
#pragma unroll
    for (int s = 0; s < 8; s++) {
        float4 x0 = *(const float4*)(gA0 + s * 32);
        float4 y0 = *(const float4*)(gA0 + s * 32 + 4);
        float4 x1 = *(const float4*)(gA1 + s * 32);
        float4 y1 = *(const float4*)(gA1 + s * 32 + 4);
        short8 a0 = pack_bf8(x0, y0);
        short8 a1 = pack_bf8(x1, y1);
        int io = s * 4 + quad;
        short8 b0 = *(const short8*)&Bls[c0i * 256 + ((io ^ k0) * 8)];
        short8 b1 = *(const short8*)&Bls[c1i * 256 + ((io ^ k1) * 8)];
        MFMA4(a0, a1, b0, b1);
    }
    if (col0 >= 768) {
#pragma unroll
        for (int nt = 0; nt < 2; nt++) {
            int c = col0 + wn * 32 + nt * 16 + l15;
            float bb = bbig[c];
#pragma unroll
            for (int mt = 0; mt < 2; mt++)
#pragma unroll
                for (int v = 0; v < 4; v++) {
                    int row = row0 + wm * 32 + mt * 16 + quad * 4 + v;
                    out0[(size_t)row * DD + (c - 768)] = acc[mt][nt][v] + bb;
                }
        }
    } else {
        int head = col0 >> 8;
        float part[2][4];
#pragma unroll
        for (int mt = 0; mt < 2; mt++)
#pragma unroll
            for (int v = 0; v < 4; v++) part[mt][v] = 0.f;
#pragma unroll
        for (int nt = 0; nt < 2; nt++) {
            int c = col0 + wn * 32 + nt * 16 + l15;
            float bb = bbig[c];
            float w2 = h2W[c];
#pragma unroll
            for (int mt = 0; mt < 2; mt++)
#pragma unroll
                for (int v = 0; v < 4; v++)
                    part[mt][v] += gelu_exact(acc[mt][nt][v] + bb) * w2;
        }
#pragma unroll
        for (int mt = 0; mt < 2; mt++)
#pragma unroll
            for (int v = 0; v < 4; v++) {
                float p = part[mt][v];
                p += __shfl_xor(p, 1); p += __shfl_xor(p, 2);
                p += __shfl_xor(p, 4); p += __shfl_xor(p, 8);
                if (l15 == 0) {
                    int row = row0 + wm * 32 + mt * 16 + quad * 4 + v;
                    atomicAdd(&outI[head * BNT + row], p);
                }
            }
    }
}

// ---------------------------------------------------------------- launch --
extern "C" void kernel_launch(void* const* d_in, const int* in_sizes, int n_in,
                              void* d_out, int out_size, void* d_ws, size_t ws_size,
                              hipStream_t stream)
{
    const int*   ids  = (const int*)d_in[0];
    const float* pos  = (const float*)d_in[1];
    const float* symt = (const float*)d_in[2];
    const float* layt = (const float*)d_in[3];
    const float* relW = (const float*)d_in[4];
    const float* relb = (const float*)d_in[5];
    const float* h1W  = (const float*)d_in[6];
    const float* h1b  = (const float*)d_in[7];
    const float* h2W  = (const float*)d_in[8];
    const float* h2b  = (const float*)d_in[9];
    const float* outW = (const float*)d_in[10];
    const float* outb = (const float*)d_in[11];
    float* out = (float*)d_out;
    float* ws  = (float*)d_ws;

    ushort* s0T  = (ushort*)(ws + OFF_S0T);
    ushort* Gc   = (ushort*)(ws + OFF_GC);
    ushort* WcT  = (ushort*)(ws + OFF_WCT);
    ushort* WbT  = (ushort*)(ws + OFF_WBT);
    float*  bbig = ws + OFF_BB;
    ushort* cnts = (ushort*)(ws + OFF_CNT);
    unsigned char* rel = (unsigned char*)(ws + OFF_REL);

    front_kernel<<<FB_TOTAL, 256, 0, stream>>>(ids, pos, symt, layt, relW, h1W, outW,
                                               h1b, outb, h2b, WcT, WbT, bbig,
                                               out + INTERP_OFF, out + SYM_OFF, s0T,
                                               rel, cnts);
    aggT_kernel<<<dim3(4, 8, 48), 256, 0, stream>>>(rel, s0T, Gc);
    projC_kernel<<<dim3(4, 64, 3), 256, 0, stream>>>(Gc, WcT, cnts, relb,
                                                     out + SYM_OFF);
    gemm2_kernel<<<dim3(16, 64), 256, 0, stream>>>(out + SYM_OFF, WbT,
                                                   bbig, h2W,
                                                   out + OUT0_OFF, out + INTERP_OFF);
}

// Round 11
// 134.918 us; speedup vs baseline: 1.3107x; 1.1983x over previous
//
#include <hip/hip_runtime.h>
#include <hip/hip_bf16.h>
#include <math.h>

#define BB 8
#define NN 512
#define DD 256
#define BNT 4096   // B*N

typedef __attribute__((ext_vector_type(8))) short short8;
typedef __attribute__((ext_vector_type(4))) float f32x4;

// Workspace layout (float offsets). ~18 MB.  (= round-0 baseline layout)
#define OFF_S0B   0u          // bf16 [4096][256]      s0 row-major (gemmT B)
#define OFF_TT    524288u     // bf16 [8][256][3072]   TT[b][e][r*512+i] = T_r[i][e]+relb_r[e]
#define OFF_WCT   6815744u    // bf16 [256][1536]      WcT[e][r*256+d] = relW[r][d][e]
#define OFF_WBT   7012352u    // bf16 [1024][256]      Wbig^T (c rows, k=d)
#define OFF_BB    7143424u    // fp32 [1024]           h1b|outb
#define OFF_REL   7144448u    // u8   [8][512][512]    relation codes (self=6)

// d_out layout (floats)
#define OUT0_OFF   0u        // output  [8][512][256]
#define INTERP_OFF 1048576u  // interp  [3][4096]
#define SYM_OFF    1060864u  // symbols [8][512][256]

__device__ __forceinline__ float gelu_exact(float x) {
    return 0.5f * x * (1.0f + erff(x * 0.70710678118654752f));
}

__device__ __forceinline__ ushort f2bf(float x) {
    __hip_bfloat16 h = __float2bfloat16(x);
    union { __hip_bfloat16 b; ushort u; } cv;
    cv.b = h;
    return cv.u;
}

// Branch-free classification (reference if/elif priority, applied in reverse).
__device__ __forceinline__ int rel_of(float dx, float dy) {
    int r = (fabsf(dx) < 0.3f && fabsf(dy) < 0.3f) ? 4 : 5;
    r = (dx >  0.5f) ? 3 : r;
    r = (dx < -0.5f) ? 2 : r;
    r = (dy < -0.5f) ? 1 : r;
    r = (dy >  0.5f) ? 0 : r;
    return r;
}

// ====== 64x64-tile MFMA core (4 waves 2x2), double-buffered LDS ===========
// (byte-identical to the 140.9 µs round-0 baseline)
// LDS [chunk(k/8)][row] ushort8 (conflict-free b128 reads). Fragments
// (m89/m91 verified): A: m=lane&15,k=quad*8+j; B: n=lane&15;
// C/D: col=lane&15, row=quad*4+reg.
#define TILE_IDS()                                             \
    const int lane = tid & 63, w = tid >> 6;                   \
    const int wm = w >> 1, wn = w & 1;                         \
    const int quad = lane >> 4, l15 = lane & 15;               \
    const int sm = tid >> 2, sq = tid & 3;

#define MFMA_STEP(Abuf, Bbuf)                                                \
    {                                                                        \
        short8 af[2], bfr[2];                                                \
        _Pragma("unroll")                                                    \
        for (int mt = 0; mt < 2; mt++)                                       \
            af[mt] = *(const short8*)&(Abuf)[(quad * 64 + wm * 32 + mt * 16 + l15) * 8]; \
        _Pragma("unroll")                                                    \
        for (int nt = 0; nt < 2; nt++)                                       \
            bfr[nt] = *(const short8*)&(Bbuf)[(quad * 64 + wn * 32 + nt * 16 + l15) * 8]; \
        _Pragma("unroll")                                                    \
        for (int mt = 0; mt < 2; mt++)                                       \
            _Pragma("unroll")                                                \
            for (int nt = 0; nt < 2; nt++)                                   \
                acc[mt][nt] = __builtin_amdgcn_mfma_f32_16x16x32_bf16(       \
                    af[mt], bfr[nt], acc[mt][nt], 0, 0, 0);                  \
    }

#define ACC_INIT()                                             \
    f32x4 acc[2][2];                                           \
    _Pragma("unroll") for (int mt = 0; mt < 2; mt++)           \
    _Pragma("unroll") for (int nt = 0; nt < 2; nt++)           \
        acc[mt][nt] = (f32x4){0.f, 0.f, 0.f, 0.f};

// front block ranges (new prep, verified-coalesced)
#define FB_TILE  0      // 160 blocks: 64x64 transpose tiles (WcT 96, h1W 48, outW 16)
#define FB_OUTI  160    // 12 blocks:  outI init (float4)
#define FB_BBIG  172    // 1 block:    bbig init
#define FB_GATH  173    // 1024 blocks: gather (4 rows/block, float4)
#define FB_CLS   1197   // 512 blocks: classify
#define FB_TOTAL 1709

// ---------------------------------------------------------------- front ---
// Coalesced prep (LDS 64x64 transpose tiles) + float4 gather + classify.
// gemmT/agg/gemm2 below are byte-identical to the 140.9 baseline.
__global__ __launch_bounds__(256) void front_kernel(
    const int* __restrict__ ids, const float* __restrict__ positions,
    const float* __restrict__ symt, const float* __restrict__ layt,
    const float* __restrict__ relW, const float* __restrict__ h1W,
    const float* __restrict__ outW, const float* __restrict__ h1b,
    const float* __restrict__ outb, const float* __restrict__ h2b,
    ushort* __restrict__ WcT, ushort* __restrict__ WbT,
    float* __restrict__ bbig, float* __restrict__ outI,
    float* __restrict__ symOut, ushort* __restrict__ s0b,
    unsigned char* __restrict__ rel)
{
    __shared__ float shbuf[64 * 65];    // 16.6 KB transpose tile / classify px,py
    int blk = blockIdx.x, tid = threadIdx.x;
    if (blk < FB_OUTI) {
        // ---- coalesced 64x64 LDS-transpose tiles (stride 65) ----
        // load: shbuf[rl][kl] = src[(srow+rl)*256 + scol+kl]   (coalesced)
        // store: dst[(drow+el)*dstride + dcol+kl] = shbuf[kl][el]  (coalesced)
        int kl = tid & 63, g4 = tid >> 6;
        const float* src; int srow, scol;
        ushort* dst; int drow, dstride, dcol;
        if (blk < 96) {                         // relW [1536][256] -> WcT[e][rd]
            int t = blk, rdt = t >> 2, et = t & 3;
            src = relW; srow = rdt * 64; scol = et * 64;
            dst = WcT; drow = et * 64; dstride = 1536; dcol = rdt * 64;
        } else if (blk < 144) {                 // h1W [r][256 d][256 e] -> WbT[r*256+e][d]
            int t = blk - 96, r = t >> 4, dt = (t >> 2) & 3, et = t & 3;
            src = h1W + (size_t)r * DD * DD; srow = dt * 64; scol = et * 64;
            dst = WbT; drow = r * 256 + et * 64; dstride = 256; dcol = dt * 64;
        } else {                                // outW [256 d][256 o] -> WbT[768+o][d]
            int t = blk - 144, dt = t >> 2, et = t & 3;
            src = outW; srow = dt * 64; scol = et * 64;
            dst = WbT; drow = 768 + et * 64; dstride = 256; dcol = dt * 64;
        }
#pragma unroll
        for (int p = 0; p < 16; p++) {
            int rl = p * 4 + g4;
            shbuf[rl * 65 + kl] = src[(size_t)(srow + rl) * 256 + scol + kl];
        }
        __syncthreads();
#pragma unroll
        for (int q = 0; q < 16; q++) {
            int el = q * 4 + g4;
            dst[(size_t)(drow + el) * dstride + dcol + kl] = f2bf(shbuf[kl * 65 + el]);
        }
    } else if (blk < FB_BBIG) {
        int idx = (blk - FB_OUTI) * 256 + tid;   // [0, 3072) float4s of outI
        float v = h2b[idx >> 10];
        ((float4*)outI)[idx] = (float4){v, v, v, v};
    } else if (blk < FB_GATH) {
        ((float4*)bbig)[tid] = (tid < 192) ? ((const float4*)h1b)[tid]
                                           : ((const float4*)outb)[tid - 192];
    } else if (blk < FB_CLS) {
        int row = (blk - FB_GATH) * 4 + (tid >> 6); // 4 rows/block
        int d = (tid & 63) * 4;
        int id = ids[row];
        float4 a = *(const float4*)&symt[(size_t)id * DD + d];
        float4 c = *(const float4*)&layt[(size_t)id * DD + d];
        float4 v = {a.x + c.x, a.y + c.y, a.z + c.z, a.w + c.w};
        *(float4*)&symOut[(size_t)row * DD + d] = v;
        union { ushort u[4]; uint2 q; } p;
        p.u[0] = f2bf(v.x); p.u[1] = f2bf(v.y); p.u[2] = f2bf(v.z); p.u[3] = f2bf(v.w);
        *(uint2*)&s0b[(size_t)row * DD + d] = p.q;
    } else {
        float* px = shbuf;
        float* py = shbuf + NN;
        int blk2 = blk - FB_CLS;                 // [0,512)
        int b = blk2 >> 6;
        int j0 = (blk2 & 63) << 3;
        int jl = tid >> 5, sub = tid & 31;       // 8 j's x 32 workers x 16 i's
        for (int i = tid; i < NN; i += 256) {
            float2 p = ((const float2*)positions)[b * NN + i];
            px[i] = p.x; py[i] = p.y;
        }
        __syncthreads();
        int j = j0 + jl;
        float xj = px[j], yj = py[j];
        union { unsigned char u8[16]; uint4 v; } codes;
#pragma unroll
        for (int t = 0; t < 16; t++) {
            int i = sub * 16 + t;
            int r = rel_of(xj - px[i], yj - py[i]);
            r = (i == j) ? 6 : r;
            codes.u8[t] = (unsigned char)r;
        }
        *(uint4*)&rel[((size_t)(b * NN + j)) * NN + sub * 16] = codes.v;
    }
}

// ----------------------------------------------------------------- gemmT --
// TT[b][e][r*512+i] = sum_d relW[r][d][e]*s0[b][i][d] + relb[r][e]
// Double-buffered; grid (8 it, 24 rm, 8 b) = 1536 blocks.   [= baseline]
__global__ __launch_bounds__(256) void gemmT_kernel(
    const ushort* __restrict__ WcT, const ushort* __restrict__ s0b,
    const float* __restrict__ relb, ushort* __restrict__ TT)
{
    __shared__ ushort Als[2][2048], Bls[2][2048];
    int tid = threadIdx.x;
    int b = blockIdx.z;
    int rowM0 = blockIdx.y * 64;           // in [0,1536): r*256+e
    int col0 = blockIdx.x * 64;            // i tile
    int r = rowM0 >> 8, e0 = rowM0 & 255;
    TILE_IDS();
    ACC_INIT();
    const ushort* gA = WcT + (size_t)(e0 + sm) * 1536 + r * 256 + sq * 8;
    const ushort* gB = s0b + ((size_t)(b * NN) + col0 + sm) * DD + sq * 8;
    const int lo = (sq * 64 + sm) * 8;

    *(uint4*)&Als[0][lo] = *(const uint4*)gA;
    *(uint4*)&Bls[0][lo] = *(const uint4*)gB;
#pragma unroll
    for (int i = 0; i < 8; i++) {
        __syncthreads();
        uint4 av2, bv2;
        if (i < 7) {
            av2 = *(const uint4*)(gA + (i + 1) * 32);
            bv2 = *(const uint4*)(gB + (i + 1) * 32);
        }
        MFMA_STEP(Als[i & 1], Bls[i & 1]);
        if (i < 7) {
            *(uint4*)&Als[(i + 1) & 1][lo] = av2;
            *(uint4*)&Bls[(i + 1) & 1][lo] = bv2;
        }
    }
#pragma unroll
    for (int mt = 0; mt < 2; mt++)
#pragma unroll
        for (int nt = 0; nt < 2; nt++)
#pragma unroll
            for (int v = 0; v < 4; v++) {
                int e = e0 + wm * 32 + mt * 16 + quad * 4 + v;
                int i = col0 + wn * 32 + nt * 16 + l15;
                TT[((size_t)(b * DD) + e) * 3072 + r * 512 + i] =
                    f2bf(acc[mt][nt][v] + relb[r * DD + e]);
            }
}

// ------------------------------------------------------------- agg gemm ---
// symOut[b*512+j][e] += sum_{r,i} 1[rel(i,j)=r] * TT[b][e][r*512+i]
// One-hot A from u8 codes; 3 K-slices (r-pairs, K=1024), grid (4,8,24).
// Double-buffered; atomicAdd into symOut (= s0 base from front). [= baseline]
__global__ __launch_bounds__(256) void agg_gemm(
    const unsigned char* __restrict__ rel, const ushort* __restrict__ TT,
    float* __restrict__ symOut)
{
    __shared__ ushort Als[2][2048], Bls[2][2048];
    int tid = threadIdx.x;
    int z = blockIdx.z;
    int b = z / 3, rg = z - b * 3;
    int row0 = blockIdx.y * 64, col0 = blockIdx.x * 64;
    TILE_IDS();
    ACC_INIT();
    const unsigned char* gC = rel + ((size_t)(b * NN + row0 + sm)) * NN;
    const ushort* gB = TT + ((size_t)(b * DD) + col0 + sm) * 3072 + rg * 1024 + sq * 8;
    const int lo = (sq * 64 + sm) * 8;

#define AGG_LOADS(i, cw, bv)                                        \
    cw = *(const uint2*)(gC + (((i) * 32 + sq * 8) & 511));         \
    bv = *(const uint4*)(gB + (i) * 32);

#define AGG_STAGE(i, cw, bv, buf)                                   \
    {                                                               \
        int rr_ = 2 * rg + (((i) * 32) >> 9);                       \
        union alignas(16) { ushort u[8]; uint4 v; } am;             \
        _Pragma("unroll")                                           \
        for (int t = 0; t < 8; t++) {                               \
            unsigned int word = (t < 4) ? cw.x : cw.y;              \
            unsigned int code = (word >> (8 * (t & 3))) & 255u;     \
            am.u[t] = (code == (unsigned)rr_) ? 0x3F80 : 0;         \
        }                                                           \
        *(uint4*)&Als[buf][lo] = am.v;                              \
        *(uint4*)&Bls[buf][lo] = bv;                                \
    }

    uint2 cw0; uint4 bv0;
    AGG_LOADS(0, cw0, bv0);
    AGG_STAGE(0, cw0, bv0, 0);
    for (int i = 0; i < 32; i++) {
        __syncthreads();
        uint2 cw2 = cw0; uint4 bv2 = bv0;
        if (i < 31) { AGG_LOADS(i + 1, cw2, bv2); }
        MFMA_STEP(Als[i & 1], Bls[i & 1]);
        if (i < 31) { AGG_STAGE(i + 1, cw2, bv2, (i + 1) & 1); }
    }
#undef AGG_LOADS
#undef AGG_STAGE
#pragma unroll
    for (int mt = 0; mt < 2; mt++)
#pragma unroll
        for (int nt = 0; nt < 2; nt++)
#pragma unroll
            for (int v = 0; v < 4; v++) {
                int j = row0 + wm * 32 + mt * 16 + quad * 4 + v;
                int e = col0 + wn * 32 + nt * 16 + l15;
                atomicAdd(&symOut[((size_t)(b * NN) + j) * DD + e], acc[mt][nt][v]);
            }
}

// ----------------------------------------------------------------- gemm2 --
// symOut(fp32, bf16 at staging) @ Wbig^T. Col tiles <768: gelu + fused
// interp reduce (atomicAdd into outI pre-loaded with h2b). Else: out0.
// [= baseline]
__global__ __launch_bounds__(256) void gemm2_kernel(
    const float* __restrict__ symOut, const ushort* __restrict__ WbT,
    const float* __restrict__ bbig, const float* __restrict__ h2W,
    float* __restrict__ out0, float* __restrict__ outI)
{
    __shared__ ushort Als[2][2048], Bls[2][2048];
    int tid = threadIdx.x;
    int row0 = blockIdx.y * 64, col0 = blockIdx.x * 64;
    TILE_IDS();
    ACC_INIT();
    const float*  gA = symOut + (size_t)(row0 + sm) * DD + sq * 8;
    const ushort* gB = WbT    + (size_t)(col0 + sm) * DD + sq * 8;
    const int lo = (sq * 64 + sm) * 8;

#define G2_LOADS(i, a0, a1, bv)                                     \
    a0 = *(const float4*)(gA + (i) * 32);                           \
    a1 = *(const float4*)(gA + (i) * 32 + 4);                       \
    bv = *(const uint4*)(gB + (i) * 32);

#define G2_STAGE(a0, a1, bv, buf)                                   \
    {                                                               \
        union alignas(16) { ushort u[8]; uint4 v; } am;             \
        am.u[0] = f2bf(a0.x); am.u[1] = f2bf(a0.y);                 \
        am.u[2] = f2bf(a0.z); am.u[3] = f2bf(a0.w);                 \
        am.u[4] = f2bf(a1.x); am.u[5] = f2bf(a1.y);                 \
        am.u[6] = f2bf(a1.z); am.u[7] = f2bf(a1.w);                 \
        *(uint4*)&Als[buf][lo] = am.v;                              \
        *(uint4*)&Bls[buf][lo] = bv;                                \
    }

    float4 a0, a1; uint4 bv;
    G2_LOADS(0, a0, a1, bv);
    G2_STAGE(a0, a1, bv, 0);
#pragma unroll
    for (int i = 0; i < 8; i++) {
        __syncthreads();
        float4 a0n = a0, a1n = a1; uint4 bvn = bv;
        if (i < 7) { G2_LOADS(i + 1, a0n, a1n, bvn); }
        MFMA_STEP(Als[i & 1], Bls[i & 1]);
        if (i < 7) { G2_STAGE(a0n, a1n, bvn, (i + 1) & 1); }
    }
#undef G2_LOADS
#undef G2_STAGE
    if (col0 >= 768) {
#pragma unroll
        for (int nt = 0; nt < 2; nt++) {
            int c = col0 + wn * 32 + nt * 16 + l15;
            float bb = bbig[c];
#pragma unroll
            for (int mt = 0; mt < 2; mt++)
#pragma unroll
                for (int v = 0; v < 4; v++) {
                    int row = row0 + wm * 32 + mt * 16 + quad * 4 + v;
                    out0[(size_t)row * DD + (c - 768)] = acc[mt][nt][v] + bb;
                }
        }
    } else {
        int head = col0 >> 8;
        float part[2][4];
#pragma unroll
        for (int mt = 0; mt < 2; mt++)
#pragma unroll
            for (int v = 0; v < 4; v++) part[mt][v] = 0.f;
#pragma unroll
        for (int nt = 0; nt < 2; nt++) {
            int c = col0 + wn * 32 + nt * 16 + l15;
            float bb = bbig[c];
            float w2 = h2W[c];
#pragma unroll
            for (int mt = 0; mt < 2; mt++)
#pragma unroll
                for (int v = 0; v < 4; v++)
                    part[mt][v] += gelu_exact(acc[mt][nt][v] + bb) * w2;
        }
#pragma unroll
        for (int mt = 0; mt < 2; mt++)
#pragma unroll
            for (int v = 0; v < 4; v++) {
                float p = part[mt][v];
                p += __shfl_xor(p, 1); p += __shfl_xor(p, 2);
                p += __shfl_xor(p, 4); p += __shfl_xor(p, 8);
                if (l15 == 0) {
                    int row = row0 + wm * 32 + mt * 16 + quad * 4 + v;
                    atomicAdd(&outI[head * BNT + row], p);
                }
            }
    }
}

// ---------------------------------------------------------------- launch --
extern "C" void kernel_launch(void* const* d_in, const int* in_sizes, int n_in,
                              void* d_out, int out_size, void* d_ws, size_t ws_size,
                              hipStream_t stream)
{
    const int*   ids  = (const int*)d_in[0];
    const float* pos  = (const float*)d_in[1];
    const float* symt = (const float*)d_in[2];
    const float* layt = (const float*)d_in[3];
    const float* relW = (const float*)d_in[4];
    const float* relb = (const float*)d_in[5];
    const float* h1W  = (const float*)d_in[6];
    const float* h1b  = (const float*)d_in[7];
    const float* h2W  = (const float*)d_in[8];
    const float* h2b  = (const float*)d_in[9];
    const float* outW = (const float*)d_in[10];
    const float* outb = (const float*)d_in[11];
    float* out = (float*)d_out;
    float* ws  = (float*)d_ws;

    ushort* s0b  = (ushort*)(ws + OFF_S0B);
    ushort* TT   = (ushort*)(ws + OFF_TT);
    ushort* WcT  = (ushort*)(ws + OFF_WCT);
    ushort* WbT  = (ushort*)(ws + OFF_WBT);
    float*  bbig = ws + OFF_BB;
    unsigned char* rel = (unsigned char*)(ws + OFF_REL);

    front_kernel<<<FB_TOTAL, 256, 0, stream>>>(ids, pos, symt, layt, relW, h1W, outW,
                                               h1b, outb, h2b, WcT, WbT, bbig,
                                               out + INTERP_OFF, out + SYM_OFF, s0b, rel);
    gemmT_kernel<<<dim3(8, 24, 8), 256, 0, stream>>>(WcT, s0b, relb, TT);
    agg_gemm<<<dim3(4, 8, 24), 256, 0, stream>>>(rel, TT, out + SYM_OFF);
    gemm2_kernel<<<dim3(16, 64), 256, 0, stream>>>(out + SYM_OFF, WbT,
                                                   bbig, h2W,
                                                   out + OUT0_OFF, out + INTERP_OFF);
}